// Round 1
// baseline (200.408 us; speedup 1.0000x reference)
//
#include <hip/hip_runtime.h>
#include <hip/hip_fp16.h>

#define N_AG 512
#define TRAJ 16
#define TAU_ 2048
#define MSG_ 32768
#define HID_ 512
#define DV_ 64
#define SPLITQ 16
#define LDS_K 40            // 32 k-halves + 8 pad -> 80B row stride: frag reads ~conflict-free
#define BUFH (128 * LDS_K)  // halves per LDS buffer (one tile side)

typedef _Float16 f16x8 __attribute__((ext_vector_type(8)));
typedef _Float16 f16x4 __attribute__((ext_vector_type(4)));
typedef float f32x4 __attribute__((ext_vector_type(4)));

// 128xNB output tile, BK=32, 256 threads = 4 waves (2x2 wave grid),
// A [128 x K] row-major fp32, B [K x NB] row-major fp32, C [128 x NB] fp32.
// fp32 -> fp16 conversion fused into LDS staging. Double-buffered, T14-style
// (issue global loads early, LDS writes after compute).
template<int NB>
__device__ __forceinline__ void gemm_tile(
    _Float16* __restrict__ As, _Float16* __restrict__ Bs,
    const float* __restrict__ Ag, int lda,
    const float* __restrict__ Bg, int ldb,
    float* __restrict__ Cg, int ldc,
    const float* __restrict__ bias, int K)
{
    constexpr int NF = NB / 32;          // B-frags per wave (4 or 2)
    const int tid = threadIdx.x;
    const int lane = tid & 63;
    const int wid = tid >> 6;
    const int wr = wid >> 1;
    const int wc = wid & 1;

    // A staging: thread -> (row, 16 consecutive k)
    const int am = tid >> 1;             // 0..127
    const int ak = (tid & 1) << 4;       // 0 or 16

    // B staging: thread -> 4k x 4n block (in-register 4x4 transpose)
    int btn, btk;
    bool bact;
    if (NB == 128) { btn = tid & 31; btk = tid >> 5; bact = true; }
    else           { btn = tid & 15; btk = (tid >> 4) & 7; bact = (tid < 128); }

    const int arow = wr * 64 + (lane & 15);
    const int brow = wc * (NF * 16) + (lane & 15);
    const int kblk = (lane >> 4) << 3;   // 8 k-halves per lane group

    f32x4 acc[4][NF];
#pragma unroll
    for (int mi = 0; mi < 4; ++mi)
#pragma unroll
        for (int ni = 0; ni < NF; ++ni)
            acc[mi][ni] = (f32x4){0.f, 0.f, 0.f, 0.f};

    float4 ra[4];
    float4 rb[4];
    const int nt = K >> 5;

    auto load_stage = [&](int ks) {
        const float* ap = Ag + am * lda + ks + ak;
#pragma unroll
        for (int i = 0; i < 4; ++i)
            ra[i] = *(const float4*)(ap + 4 * i);
        if (bact) {
            const float* bp = Bg + (ks + btk * 4) * ldb + btn * 4;
#pragma unroll
            for (int i = 0; i < 4; ++i)
                rb[i] = *(const float4*)(bp + i * ldb);
        }
    };

    auto write_stage = [&](int buf) {
        _Float16* abase = As + buf * BUFH + am * LDS_K + ak;
        const float* fa = (const float*)ra;
        f16x8 h0, h1;
#pragma unroll
        for (int i = 0; i < 8; ++i) { h0[i] = (_Float16)fa[i]; h1[i] = (_Float16)fa[8 + i]; }
        *(f16x8*)abase = h0;
        *(f16x8*)(abase + 8) = h1;
        if (bact) {
            const float* fb = (const float*)rb;
#pragma unroll
            for (int j = 0; j < 4; ++j) {
                f16x4 w;
#pragma unroll
                for (int i = 0; i < 4; ++i) w[i] = (_Float16)fb[i * 4 + j];
                *(f16x4*)(Bs + buf * BUFH + (btn * 4 + j) * LDS_K + btk * 4) = w;
            }
        }
    };

    auto compute = [&](int buf) {
        const _Float16* ab = As + buf * BUFH;
        const _Float16* bb = Bs + buf * BUFH;
        f16x8 af[4], bf[NF];
#pragma unroll
        for (int mi = 0; mi < 4; ++mi)
            af[mi] = *(const f16x8*)(ab + (arow + mi * 16) * LDS_K + kblk);
#pragma unroll
        for (int ni = 0; ni < NF; ++ni)
            bf[ni] = *(const f16x8*)(bb + (brow + ni * 16) * LDS_K + kblk);
#pragma unroll
        for (int mi = 0; mi < 4; ++mi)
#pragma unroll
            for (int ni = 0; ni < NF; ++ni)
                acc[mi][ni] = __builtin_amdgcn_mfma_f32_16x16x32_f16(
                    af[mi], bf[ni], acc[mi][ni], 0, 0, 0);
    };

    load_stage(0);
    write_stage(0);
    __syncthreads();
    for (int t = 0; t < nt; ++t) {
        const int cur = t & 1;
        if (t + 1 < nt) load_stage((t + 1) << 5);
        compute(cur);
        if (t + 1 < nt) write_stage(cur ^ 1);
        __syncthreads();
    }

    // C/D layout (HW-verified): col = lane&15, row = (lane>>4)*4 + reg
#pragma unroll
    for (int mi = 0; mi < 4; ++mi) {
#pragma unroll
        for (int ni = 0; ni < NF; ++ni) {
            const int row = wr * 64 + mi * 16 + ((lane >> 4) << 2);
            const int col = wc * (NF * 16) + ni * 16 + (lane & 15);
            const float badd = bias ? bias[col] : 0.f;
#pragma unroll
            for (int r = 0; r < 4; ++r)
                Cg[(row + r) * ldc + col] = acc[mi][ni][r] + badd;
        }
    }
}

// q = X @ Wq, split-K=16: each block writes one [128x128] tile of one K-slice partial.
__global__ __launch_bounds__(256, 2) void qgemm(const float* __restrict__ X,
                                                const float* __restrict__ Wq,
                                                float* __restrict__ qpart)
{
    __shared__ __align__(16) _Float16 smem[4 * BUFH];
    const int bm = blockIdx.x >> 2;
    const int bn = blockIdx.x & 3;
    const int s = blockIdx.y;
    gemm_tile<128>(smem, smem + 2 * BUFH,
                   X + bm * 128 * MSG_ + s * (MSG_ / SPLITQ), MSG_,
                   Wq + (s * (MSG_ / SPLITQ)) * HID_ + bn * 128, HID_,
                   qpart + s * (N_AG * HID_) + bm * 128 * HID_ + bn * 128, HID_,
                   nullptr, MSG_ / SPLITQ);
}

// k = taus @ Wk + bk (bn 0..3); v = taus @ Wv + bv (bn == 4, shares taus panels via L2)
__global__ __launch_bounds__(256, 2) void kvgemm(const float* __restrict__ Tr,
                                                 const float* __restrict__ Wk,
                                                 const float* __restrict__ bk,
                                                 const float* __restrict__ Wv,
                                                 const float* __restrict__ bv,
                                                 float* __restrict__ kout,
                                                 float* __restrict__ vout)
{
    __shared__ __align__(16) _Float16 smem[4 * BUFH];
    const int bm = blockIdx.x;
    const int bn = blockIdx.y;
    const float* Ag = Tr + bm * 128 * TAU_;
    if (bn < 4) {
        gemm_tile<128>(smem, smem + 2 * BUFH, Ag, TAU_,
                       Wk + bn * 128, HID_,
                       kout + bm * 128 * HID_ + bn * 128, HID_,
                       bk + bn * 128, TAU_);
    } else {
        gemm_tile<64>(smem, smem + 2 * BUFH, Ag, TAU_,
                      Wv, DV_,
                      vout + bm * 128 * DV_, DV_,
                      bv, TAU_);
    }
}

// Per-agent: reduce q split-K partials (+bq), 16 dots via wave shuffle-reduce,
// softmax, weighted V sum (+bv).
__global__ __launch_bounds__(256) void attn(const float* __restrict__ qpart,
                                            const float* __restrict__ kmat,
                                            const float* __restrict__ vmat,
                                            const float* __restrict__ bq,
                                            const float* __restrict__ bv,
                                            float* __restrict__ out)
{
    const int n = blockIdx.x;
    const int tid = threadIdx.x;
    __shared__ float qs[HID_];
    __shared__ float scr[TRAJ];

    for (int h = tid; h < HID_; h += 256) {
        float a = bq[h];
#pragma unroll
        for (int s = 0; s < SPLITQ; ++s)
            a += qpart[s * (N_AG * HID_) + n * HID_ + h];
        qs[h] = a;
    }
    __syncthreads();

    const int w = tid >> 6;
    const int lane = tid & 63;
#pragma unroll
    for (int tt = 0; tt < 4; ++tt) {
        const int t = w * 4 + tt;
        const float* kr = kmat + (t * N_AG + n) * HID_;
        const int h0 = lane * 8;
        float4 k0 = *(const float4*)(kr + h0);
        float4 k1 = *(const float4*)(kr + h0 + 4);
        float p = qs[h0] * k0.x + qs[h0 + 1] * k0.y + qs[h0 + 2] * k0.z + qs[h0 + 3] * k0.w
                + qs[h0 + 4] * k1.x + qs[h0 + 5] * k1.y + qs[h0 + 6] * k1.z + qs[h0 + 7] * k1.w;
#pragma unroll
        for (int off = 32; off > 0; off >>= 1)
            p += __shfl_xor(p, off);
        if (lane == 0) scr[t] = p;
    }
    __syncthreads();

    const float inv = 0.04419417382415922f;  // 1/sqrt(512)
    float sv[TRAJ];
    float mx = -1e30f;
#pragma unroll
    for (int t = 0; t < TRAJ; ++t) { sv[t] = scr[t] * inv; mx = fmaxf(mx, sv[t]); }
    float ssum = 0.f;
#pragma unroll
    for (int t = 0; t < TRAJ; ++t) { sv[t] = expf(sv[t] - mx); ssum += sv[t]; }
    const float rs = 1.f / ssum;

    if (tid < DV_) {
        float o = bv[tid];
#pragma unroll
        for (int t = 0; t < TRAJ; ++t)
            o += sv[t] * rs * vmat[(t * N_AG + n) * DV_ + tid];
        out[n * DV_ + tid] = o;
    }
}

extern "C" void kernel_launch(void* const* d_in, const int* in_sizes, int n_in,
                              void* d_out, int out_size, void* d_ws, size_t ws_size,
                              hipStream_t stream)
{
    const float* traj = (const float*)d_in[0];  // [16, 512, 2048] == taus [8192, 2048]
    const float* msgs = (const float*)d_in[1];  // [512, 32768]
    const float* Wq   = (const float*)d_in[2];  // [32768, 512]
    const float* bq   = (const float*)d_in[3];  // [512]
    const float* Wk   = (const float*)d_in[4];  // [2048, 512]
    const float* bk   = (const float*)d_in[5];  // [512]
    const float* Wv   = (const float*)d_in[6];  // [2048, 64]
    const float* bv   = (const float*)d_in[7];  // [64]
    float* out = (float*)d_out;                 // [512, 64]

    // ws: qpart [16][512][512] (16MB) | k [8192][512] (16MB) | v [8192][64] (2MB)
    float* qpart = (float*)d_ws;
    float* kmat = qpart + (size_t)SPLITQ * N_AG * HID_;
    float* vmat = kmat + (size_t)TRAJ * N_AG * HID_;

    qgemm<<<dim3(16, 16), 256, 0, stream>>>(msgs, Wq, qpart);
    kvgemm<<<dim3(64, 5), 256, 0, stream>>>(traj, Wk, bk, Wv, bv, kmat, vmat);
    attn<<<512, 256, 0, stream>>>(qpart, kmat, vmat, bq, bv, out);
}

// Round 2
// 110.963 us; speedup vs baseline: 1.8061x; 1.8061x over previous
//
#include <hip/hip_runtime.h>
#include <hip/hip_fp16.h>

#define N_AG 512
#define TRAJ 16
#define TAU_ 2048
#define MSG_ 32768
#define HID_ 512
#define DV_ 64
#define SPLITQ 32
#define LDS_K 40            // 32 k-halves + 8 pad -> 80B row stride (16B-aligned rows)
#define BUFH (128 * LDS_K)  // halves per LDS buffer side

typedef _Float16 f16x8 __attribute__((ext_vector_type(8)));
typedef _Float16 f16x4 __attribute__((ext_vector_type(4)));
typedef _Float16 f16x2 __attribute__((ext_vector_type(2)));
typedef float f32x4 __attribute__((ext_vector_type(4)));

// 128xNB tile, BK=32, 256 threads = 4 waves (2x2), A [128 x K] row-major fp32,
// B [K x NB] row-major fp32, C fp16. fp32->fp16 cast fused into LDS staging.
// 2-deep register prefetch: loads for tile t+2 issued at iter t (two named reg
// buffers -> all static indexing), LDS write after compute (T14 style).
template<int NB>
__device__ __forceinline__ void gemm_tile(
    _Float16* __restrict__ As, _Float16* __restrict__ Bs,
    const float* __restrict__ Ag, int lda,
    const float* __restrict__ Bg, int ldb,
    _Float16* __restrict__ Cg, int ldc,
    const float* __restrict__ bias, int K)
{
    constexpr int NF = NB / 32;
    const int tid = threadIdx.x;
    const int lane = tid & 63;
    const int wid = tid >> 6;
    const int wr = wid >> 1;
    const int wc = wid & 1;

    const int am = tid >> 1;
    const int ak = (tid & 1) << 4;

    int btn, btk;
    bool bact;
    if (NB == 128) { btn = tid & 31; btk = tid >> 5; bact = true; }
    else           { btn = tid & 15; btk = (tid >> 4) & 7; bact = (tid < 128); }

    const int arow = wr * 64 + (lane & 15);
    const int brow = wc * (NF * 16) + (lane & 15);
    const int kblk = (lane >> 4) << 3;

    f32x4 acc[4][NF];
#pragma unroll
    for (int mi = 0; mi < 4; ++mi)
#pragma unroll
        for (int ni = 0; ni < NF; ++ni)
            acc[mi][ni] = (f32x4){0.f, 0.f, 0.f, 0.f};

    float4 rA[8], rB[8];  // [0..3] = A frag, [4..7] = B frag
    const int nt = K >> 5;  // must be even, >= 4

    auto load_stage = [&](float4 (&r)[8], int ks) {
        const float* ap = Ag + (size_t)am * lda + ks + ak;
#pragma unroll
        for (int i = 0; i < 4; ++i)
            r[i] = *(const float4*)(ap + 4 * i);
        if (bact) {
            const float* bp = Bg + (size_t)(ks + btk * 4) * ldb + btn * 4;
#pragma unroll
            for (int i = 0; i < 4; ++i)
                r[4 + i] = *(const float4*)(bp + (size_t)i * ldb);
        }
    };

    auto write_stage = [&](float4 (&r)[8], int buf) {
        _Float16* abase = As + buf * BUFH + am * LDS_K + ak;
        const float* fa = (const float*)&r[0];
        f16x8 h0, h1;
#pragma unroll
        for (int i = 0; i < 8; ++i) { h0[i] = (_Float16)fa[i]; h1[i] = (_Float16)fa[8 + i]; }
        *(f16x8*)abase = h0;
        *(f16x8*)(abase + 8) = h1;
        if (bact) {
            const float* fb = (const float*)&r[4];
#pragma unroll
            for (int j = 0; j < 4; ++j) {
                f16x4 w;
#pragma unroll
                for (int i = 0; i < 4; ++i) w[i] = (_Float16)fb[i * 4 + j];
                *(f16x4*)(Bs + buf * BUFH + (btn * 4 + j) * LDS_K + btk * 4) = w;
            }
        }
    };

    auto compute = [&](int buf) {
        const _Float16* ab = As + buf * BUFH;
        const _Float16* bb = Bs + buf * BUFH;
        f16x8 af[4], bf[NF];
#pragma unroll
        for (int mi = 0; mi < 4; ++mi)
            af[mi] = *(const f16x8*)(ab + (arow + mi * 16) * LDS_K + kblk);
#pragma unroll
        for (int ni = 0; ni < NF; ++ni)
            bf[ni] = *(const f16x8*)(bb + (brow + ni * 16) * LDS_K + kblk);
#pragma unroll
        for (int mi = 0; mi < 4; ++mi)
#pragma unroll
            for (int ni = 0; ni < NF; ++ni)
                acc[mi][ni] = __builtin_amdgcn_mfma_f32_16x16x32_f16(
                    af[mi], bf[ni], acc[mi][ni], 0, 0, 0);
    };

    load_stage(rA, 0);
    load_stage(rB, 32);
    write_stage(rA, 0);
    __syncthreads();

    for (int t = 0; t < nt; t += 2) {
        if (t + 2 < nt) load_stage(rA, (t + 2) << 5);
        compute(0);
        if (t + 1 < nt) write_stage(rB, 1);
        __syncthreads();
        if (t + 3 < nt) load_stage(rB, (t + 3) << 5);
        compute(1);
        if (t + 2 < nt) write_stage(rA, 0);
        __syncthreads();
    }

    // C/D layout (HW-verified): col = lane&15, row = (lane>>4)*4 + reg
#pragma unroll
    for (int mi = 0; mi < 4; ++mi) {
#pragma unroll
        for (int ni = 0; ni < NF; ++ni) {
            const int row = wr * 64 + mi * 16 + ((lane >> 4) << 2);
            const int col = wc * (NF * 16) + ni * 16 + (lane & 15);
            const float badd = bias ? bias[col] : 0.f;
#pragma unroll
            for (int r = 0; r < 4; ++r)
                Cg[(size_t)(row + r) * ldc + col] = (_Float16)(acc[mi][ni][r] + badd);
        }
    }
}

// q partials: split-K=32 (1024 each), grid 512 blocks (2/CU). XCD-chunked swizzle.
__global__ __launch_bounds__(256, 2) void qgemm(const float* __restrict__ X,
                                                const float* __restrict__ Wq,
                                                _Float16* __restrict__ qpart)
{
    __shared__ __align__(16) _Float16 smem[4 * BUFH];
    const int b = blockIdx.x;
    const int w = (b & 7) * 64 + (b >> 3);   // 512 = 8 XCD chunks of 64
    const int s = w >> 4;                    // K-slice 0..31
    const int bm = (w >> 2) & 3;
    const int bn = w & 3;
    const int KS = MSG_ / SPLITQ;            // 1024
    gemm_tile<128>(smem, smem + 2 * BUFH,
                   X + (size_t)bm * 128 * MSG_ + s * KS, MSG_,
                   Wq + (size_t)(s * KS) * HID_ + bn * 128, HID_,
                   qpart + (size_t)s * (N_AG * HID_) + bm * 128 * HID_ + bn * 128, HID_,
                   nullptr, KS);
}

// k (bn 0..7, 64-col tiles) and v (bn==8), no K-split: grid 576 (2.25/CU).
__global__ __launch_bounds__(256, 2) void kvgemm(const float* __restrict__ Tr,
                                                 const float* __restrict__ Wk,
                                                 const float* __restrict__ bk,
                                                 const float* __restrict__ Wv,
                                                 const float* __restrict__ bv,
                                                 _Float16* __restrict__ kout,
                                                 _Float16* __restrict__ vout)
{
    __shared__ __align__(16) _Float16 smem[4 * BUFH];
    const int b = blockIdx.x;
    const int w = (b & 7) * 72 + (b >> 3);   // 576 = 8 XCD chunks of 72
    const int bm = w / 9;
    const int bn = w % 9;
    const float* Ag = Tr + (size_t)bm * 128 * TAU_;
    if (bn < 8) {
        gemm_tile<64>(smem, smem + 2 * BUFH, Ag, TAU_,
                      Wk + bn * 64, HID_,
                      kout + (size_t)bm * 128 * HID_ + bn * 64, HID_,
                      bk + bn * 64, TAU_);
    } else {
        gemm_tile<64>(smem, smem + 2 * BUFH, Ag, TAU_,
                      Wv, DV_,
                      vout + (size_t)bm * 128 * DV_, DV_,
                      bv, TAU_);
    }
}

// Per-agent: reduce fp16 q-partials (+bq), 16 dots via shuffle-reduce, softmax, PV.
__global__ __launch_bounds__(256) void attn(const _Float16* __restrict__ qpart,
                                            const _Float16* __restrict__ kmat,
                                            const _Float16* __restrict__ vmat,
                                            const float* __restrict__ bq,
                                            const float* __restrict__ bv,
                                            float* __restrict__ out)
{
    const int n = blockIdx.x;
    const int tid = threadIdx.x;
    __shared__ float qs[HID_];
    __shared__ float scr[TRAJ];

    {
        const int h2 = tid * 2;
        float a0 = bq[h2], a1 = bq[h2 + 1];
#pragma unroll
        for (int s = 0; s < SPLITQ; ++s) {
            f16x2 p = *(const f16x2*)(qpart + (size_t)s * (N_AG * HID_) + n * HID_ + h2);
            a0 += (float)p[0];
            a1 += (float)p[1];
        }
        qs[h2] = a0;
        qs[h2 + 1] = a1;
    }
    __syncthreads();

    const int w = tid >> 6;
    const int lane = tid & 63;
#pragma unroll
    for (int tt = 0; tt < 4; ++tt) {
        const int t = w * 4 + tt;
        const _Float16* kr = kmat + (size_t)(t * N_AG + n) * HID_;
        const int h0 = lane * 8;
        f16x8 kv = *(const f16x8*)(kr + h0);
        float p = 0.f;
#pragma unroll
        for (int i = 0; i < 8; ++i)
            p += qs[h0 + i] * (float)kv[i];
#pragma unroll
        for (int off = 32; off > 0; off >>= 1)
            p += __shfl_xor(p, off);
        if (lane == 0) scr[t] = p;
    }
    __syncthreads();

    const float inv = 0.04419417382415922f;  // 1/sqrt(512)
    float sv[TRAJ];
    float mx = -1e30f;
#pragma unroll
    for (int t = 0; t < TRAJ; ++t) { sv[t] = scr[t] * inv; mx = fmaxf(mx, sv[t]); }
    float ssum = 0.f;
#pragma unroll
    for (int t = 0; t < TRAJ; ++t) { sv[t] = expf(sv[t] - mx); ssum += sv[t]; }
    const float rs = 1.f / ssum;

    if (tid < DV_) {
        float o = bv[tid];
#pragma unroll
        for (int t = 0; t < TRAJ; ++t)
            o += sv[t] * rs * (float)vmat[(size_t)(t * N_AG + n) * DV_ + tid];
        out[n * DV_ + tid] = o;
    }
}

extern "C" void kernel_launch(void* const* d_in, const int* in_sizes, int n_in,
                              void* d_out, int out_size, void* d_ws, size_t ws_size,
                              hipStream_t stream)
{
    const float* traj = (const float*)d_in[0];  // [16,512,2048] == taus [8192,2048]
    const float* msgs = (const float*)d_in[1];  // [512, 32768]
    const float* Wq   = (const float*)d_in[2];  // [32768, 512]
    const float* bq   = (const float*)d_in[3];  // [512]
    const float* Wk   = (const float*)d_in[4];  // [2048, 512]
    const float* bk   = (const float*)d_in[5];  // [512]
    const float* Wv   = (const float*)d_in[6];  // [2048, 64]
    const float* bv   = (const float*)d_in[7];  // [64]
    float* out = (float*)d_out;                 // [512, 64]

    // ws (fp16): qpart [32][512][512] 16MB | k [8192][512] 8MB | v [8192][64] 1MB
    _Float16* qpart = (_Float16*)d_ws;
    _Float16* kmat = qpart + (size_t)SPLITQ * N_AG * HID_;
    _Float16* vmat = kmat + (size_t)TRAJ * N_AG * HID_;

    qgemm<<<512, 256, 0, stream>>>(msgs, Wq, qpart);
    kvgemm<<<576, 256, 0, stream>>>(traj, Wk, bk, Wv, bv, kmat, vmat);
    attn<<<512, 256, 0, stream>>>(qpart, kmat, vmat, bq, bv, out);
}